// Round 1
// baseline (6057.223 us; speedup 1.0000x reference)
//
#include <hip/hip_runtime.h>
#include <cstdint>
#include <cstddef>

// ---------------------------------------------------------------------------
// RNN_42537356100303: 3-layer tanh RNN (B=128,T=1024,F=24,H=512) + MLP head.
// Phase plan (all on one in-place f16 buffer P[B*T, 512] in ws):
//   k_cvt   : fp32 weights -> f16, bias_l = b_ih+b_hh, zero the X handshake buf
//   k_xp0   : P = x @ W_ih0^T + bias0            (VALU, K=24)
//   k_scan2 : P[b,t,:] = h_t  (in-place over xp). TWO WGs per batch (256 WGs =
//             all 256 CUs): WG (b, hf) owns rows [hf*256, hf*256+256). Inside a
//             WG, 2 threads per row k-split the dot (256 cols each), so the
//             W_hh half-row fits entirely in VGPRs (32 uint4) -- zero per-lane
//             LDS W reads. Pair-reduce via shfl_xor. Cross-WG h exchange via
//             packed {tag,h} u64 agent-scope atomics, double-buffered by t&1.
//   k_proj  : P = P @ W_ih^T + bias  (in-place row-block MFMA f16 GEMM)
//   k_head  : out = silu(last @ W1^T + b1) @ W2^T + b2
// ---------------------------------------------------------------------------

typedef _Float16 half_t;
typedef __attribute__((ext_vector_type(2))) _Float16 half2_t;
typedef __attribute__((ext_vector_type(8))) _Float16 frag8;
typedef __attribute__((ext_vector_type(4))) float    frag4;

union U32H2 { unsigned u; half2_t h2; };
union HU16 { _Float16 h; unsigned short u; };

__device__ __forceinline__ float dot2(unsigned a, unsigned b, float c) {
#if __has_builtin(__builtin_amdgcn_fdot2)
    U32H2 ua; ua.u = a; U32H2 ub; ub.u = b;
    return __builtin_amdgcn_fdot2(ua.h2, ub.h2, c, false);
#else
    U32H2 ua; ua.u = a; U32H2 ub; ub.u = b;
    c += (float)ua.h2.x * (float)ub.h2.x;
    c += (float)ua.h2.y * (float)ub.h2.y;
    return c;
#endif
}

__device__ __forceinline__ float fast_tanh(float x) {
    float ax = __builtin_fabsf(x);
    float e  = __expf(-2.f * ax);          // v_exp_f32 path
    float r  = (1.f - e) / (1.f + e);
    return __builtin_copysignf(r, x);
}

#define WN (512 * 512)
// X handshake buffer: [par=2][b=128][hf=2][row=256] u64 slots
#define XPAR_STRIDE (128 * 2 * 256)
#define XSLOTS (2 * XPAR_STRIDE)

// -------------------------------------------------------------- k_cvt ------
__global__ __launch_bounds__(256) void k_cvt(
    const float* whh0, const float* whh1, const float* whh2,
    const float* wih1, const float* wih2,
    const float* bi0, const float* bh0, const float* bi1, const float* bh1,
    const float* bi2, const float* bh2,
    half_t* w16, float* bias, unsigned long long* X)
{
    int idx = blockIdx.x * 256 + threadIdx.x;
    if (idx < XSLOTS) X[idx] = 0ull;        // re-arm handshake tags (replay-safe)
    if (idx < 5 * WN) {
        int seg = idx / WN, off = idx % WN;
        const float* s = seg == 0 ? whh0 : seg == 1 ? whh1 : seg == 2 ? whh2
                       : seg == 3 ? wih1 : wih2;
        w16[idx] = (half_t)s[off];
    } else {
        int j = idx - 5 * WN;
        if (j < 3 * 512) {
            int l = j >> 9, o = j & 511;
            const float* a = l == 0 ? bi0 : l == 1 ? bi1 : bi2;
            const float* c = l == 0 ? bh0 : l == 1 ? bh1 : bh2;
            bias[j] = a[o] + c[o];
        }
    }
}

// -------------------------------------------------------------- k_xp0 ------
__global__ __launch_bounds__(256) void k_xp0(
    const float* __restrict__ x, const float* __restrict__ wih0,
    const float* __restrict__ bias0, half_t* __restrict__ P)
{
    __shared__ float wl[512 * 24];
    __shared__ float xl[32 * 25];
    int tid = threadIdx.x;
    int r0  = blockIdx.x * 32;
    for (int i = tid; i < 512 * 24; i += 256) wl[i] = wih0[i];
    for (int i = tid; i < 32 * 24; i += 256) {
        int r = i / 24, f = i % 24;
        xl[r * 25 + f] = x[(size_t)(r0 + r) * 24 + f];
    }
    __syncthreads();
    int r = tid >> 3, c = tid & 7;
    float xr[24];
#pragma unroll
    for (int f = 0; f < 24; f++) xr[f] = xl[r * 25 + f];
    size_t orow = (size_t)(r0 + r) * 512;
    for (int og = 0; og < 8; og++) {
        half_t hv[8];
#pragma unroll
        for (int oj = 0; oj < 8; oj++) {
            int o = og * 64 + c * 8 + oj;
            float acc = bias0[o];
#pragma unroll
            for (int f = 0; f < 24; f++) acc = fmaf(xr[f], wl[o * 24 + f], acc);
            hv[oj] = (half_t)acc;
        }
        *(uint4*)(P + orow + og * 64 + c * 8) = *(const uint4*)hv;
    }
}

// -------------------------------------------------------------- k_scan2 ----
// Grid: 256 WGs x 512 threads. WG g: batch b = g&127, half hf = g>>7, owns
// output rows [hf*256, hf*256+256). Thread tid: row rl = tid>>1, k-half
// kh = tid&1 (cols [kh*256, kh*256+256)). W half-row = 32 uint4 in VGPRs.
// h double-buffered in LDS (full 512 f16); partner half arrives via X.
__global__ __launch_bounds__(512, 2) void k_scan2(
    half_t* __restrict__ P, const half_t* __restrict__ whh,
    unsigned long long* __restrict__ X, int tag_base)
{
    __shared__ __align__(16) _Float16 sh[2][512];

    int tid = threadIdx.x;
    int g   = blockIdx.x;
    int b   = g & 127, hf = g >> 7;
    int rl  = tid >> 1;                 // 0..255
    int kh  = tid & 1;                  // k half
    int row = hf * 256 + rl;            // my output row

    // W_hh half-row -> registers (32 uint4 = 128 VGPR)
    const uint4* wrow = (const uint4*)(whh + (size_t)row * 512 + kh * 256);
    uint4 wreg[32];
#pragma unroll
    for (int i = 0; i < 32; i++) wreg[i] = wrow[i];

    sh[0][tid] = (_Float16)0.f;         // h_{-1} = 0
    __syncthreads();

    half_t* Pb = P + (size_t)b * 1024 * 512;
    unsigned long long* Xpub  = X + (size_t)(b * 2 + hf) * 256;
    unsigned long long* Xpoll = X + (size_t)(b * 2 + (1 - hf)) * 256;

    float xp_next = (kh == 0) ? (float)Pb[row] : 0.f;   // xp_0 prefetch

    for (int t = 0; t < 1024; ++t) {
        int cur = t & 1, nxt = cur ^ 1;
        const uint4* h4 = (const uint4*)&sh[cur][kh * 256];

        float a0 = 0.f, a1 = 0.f, a2 = 0.f, a3 = 0.f;
#pragma unroll
        for (int i = 0; i < 32; i++) {          // 128 dot2 over my k-half
            uint4 hv = h4[i];
            uint4 wv = wreg[i];
            a0 = dot2(wv.x, hv.x, a0);
            a1 = dot2(wv.y, hv.y, a1);
            a2 = dot2(wv.z, hv.z, a2);
            a3 = dot2(wv.w, hv.w, a3);
        }
        float red = (a0 + a1) + (a2 + a3);
        red += __shfl_xor(red, 1);              // pair reduce (k-halves)

        size_t par = (size_t)(t & 1) * XPAR_STRIDE;
        if (kh == 0) {                          // row owner
            float hn = fast_tanh(red + xp_next);
            half_t hh = (half_t)hn;
            sh[nxt][row] = hh;                  // my half, local
            Pb[(size_t)t * 512 + row] = hh;     // in-place over xp
            HU16 hu; hu.h = hh;
            unsigned long long pk =
                ((unsigned long long)(unsigned)(tag_base + t + 1) << 32)
                | (unsigned long long)hu.u;
            __hip_atomic_store(&Xpub[par + rl], pk,
                               __ATOMIC_RELAXED, __HIP_MEMORY_SCOPE_AGENT);
            int tn = t + 1 < 1024 ? t + 1 : 1023;
            xp_next = (float)Pb[(size_t)tn * 512 + row];  // prefetch next xp
        }
        if (tid < 256 && t < 1023) {            // fetch partner half of h_t
            unsigned need = (unsigned)(tag_base + t + 1);
            unsigned long long v;
            do {
                v = __hip_atomic_load(&Xpoll[par + tid],
                                      __ATOMIC_RELAXED, __HIP_MEMORY_SCOPE_AGENT);
            } while ((unsigned)(v >> 32) < need);
            HU16 hu; hu.u = (unsigned short)(v & 0xffffull);
            sh[nxt][(1 - hf) * 256 + tid] = hu.h;
        }
        __syncthreads();
    }
}

// -------------------------------------------------------------- k_proj -----
// In-place row-block GEMM: rows [r0, r0+64) of P times W^T (W = [512 o][512 k]
// f16), + bias, overwrite. MFMA f32_16x16x32_f16.
__global__ __launch_bounds__(256, 2) void k_proj(
    half_t* __restrict__ P, const half_t* __restrict__ w16,
    const float* __restrict__ bias)
{
    extern __shared__ char smem[];
    half_t* A = (half_t*)smem;                  // 64 rows x stride 520 (65 KB)
    const int AS = 520;
    int tid = threadIdx.x;
    size_t r0 = (size_t)blockIdx.x * 64;

    const uint4* Pg = (const uint4*)(P + r0 * 512);
    for (int u = tid; u < 4096; u += 256) {     // 64 rows x 64 uint4
        uint4 v = Pg[u];
        int row = u >> 6, col = u & 63;
        *(uint4*)(A + row * AS + col * 8) = v;
    }
    __syncthreads();

    int wave = tid >> 6, lane = tid & 63;
    int lm = lane & 15, lq = lane >> 4;

    frag4 acc[4][8];
#pragma unroll
    for (int mt = 0; mt < 4; mt++)
#pragma unroll
        for (int nt = 0; nt < 8; nt++) acc[mt][nt] = (frag4){0.f, 0.f, 0.f, 0.f};

    for (int kb = 0; kb < 16; kb++) {
        int k0 = kb * 32 + lq * 8;
        frag8 af[4];
#pragma unroll
        for (int mt = 0; mt < 4; mt++)
            af[mt] = *(const frag8*)(A + (mt * 16 + lm) * AS + k0);
        frag8 bf[8];
#pragma unroll
        for (int nt = 0; nt < 8; nt++) {
            int n = wave * 128 + nt * 16 + lm;
            bf[nt] = *(const frag8*)(w16 + (size_t)n * 512 + k0);
        }
#pragma unroll
        for (int mt = 0; mt < 4; mt++)
#pragma unroll
            for (int nt = 0; nt < 8; nt++)
                acc[mt][nt] = __builtin_amdgcn_mfma_f32_16x16x32_f16(
                    af[mt], bf[nt], acc[mt][nt], 0, 0, 0);
    }

#pragma unroll
    for (int mt = 0; mt < 4; mt++) {
        int row = mt * 16 + lq * 4;
#pragma unroll
        for (int nt = 0; nt < 8; nt++) {
            int oc = wave * 128 + nt * 16 + lm;
            float bo = bias[oc];
#pragma unroll
            for (int i = 0; i < 4; i++) {
                float v = acc[mt][nt][i] + bo;
                P[(r0 + row + i) * 512 + oc] = (half_t)v;
            }
        }
    }
}

// -------------------------------------------------------------- k_head -----
__global__ __launch_bounds__(256) void k_head(
    const half_t* __restrict__ P, const float* __restrict__ W1,
    const float* __restrict__ b1, const float* __restrict__ W2,
    const float* __restrict__ b2, float* __restrict__ out)
{
    __shared__ float lastv[512];
    __shared__ float zl[1024];
    __shared__ float red[8][33];
    int tid = threadIdx.x, b = blockIdx.x;
    const half_t* lr = P + ((size_t)b * 1024 + 1023) * 512;
    lastv[tid]       = (float)lr[tid];
    lastv[tid + 256] = (float)lr[tid + 256];
    __syncthreads();
#pragma unroll
    for (int i = 0; i < 4; i++) {
        int m = tid + 256 * i;
        const float* wr = W1 + (size_t)m * 512;
        float acc = b1[m];
        for (int k = 0; k < 512; k += 4) {
            float4 wv = *(const float4*)(wr + k);
            acc = fmaf(wv.x, lastv[k],     acc);
            acc = fmaf(wv.y, lastv[k + 1], acc);
            acc = fmaf(wv.z, lastv[k + 2], acc);
            acc = fmaf(wv.w, lastv[k + 3], acc);
        }
        zl[m] = acc / (1.f + __expf(-acc));         // silu
    }
    __syncthreads();
    int c = tid & 7, mc = tid >> 3;                 // 8 outputs x 32 m-chunks
    float p = 0.f;
#pragma unroll
    for (int j = 0; j < 32; j++) {
        int m = mc * 32 + j;
        p = fmaf(zl[m], W2[c * 1024 + m], p);
    }
    red[c][mc] = p;
    __syncthreads();
    if (tid < 8) {
        float s = b2[tid];
#pragma unroll
        for (int j = 0; j < 32; j++) s += red[tid][j];
        out[b * 8 + tid] = s;
    }
}

// ---------------------------------------------------------------------------
static inline void launch_scan(half_t* P, const half_t* whh,
                               unsigned long long* X, int tag_base,
                               hipStream_t stream)
{
    half_t* Pp = P;
    const half_t* Wp = whh;
    unsigned long long* Xp = X;
    int tb = tag_base;
    void* args[] = {&Pp, &Wp, &Xp, &tb};
    // Cooperative launch guarantees all 256 WGs co-resident (1 WG/CU).
    // Fallback: plain launch; grid=256 with __launch_bounds__(512,2) still
    // fits 1 WG/CU chip-wide on an exclusive stream.
    if (hipLaunchCooperativeKernel((const void*)k_scan2, dim3(256), dim3(512),
                                   args, 0u, stream) != hipSuccess) {
        k_scan2<<<256, 512, 0, stream>>>(Pp, Wp, Xp, tb);
    }
}

extern "C" void kernel_launch(void* const* d_in, const int* in_sizes, int n_in,
                              void* d_out, int out_size, void* d_ws, size_t ws_size,
                              hipStream_t stream)
{
    const float* x    = (const float*)d_in[0];
    const float* wih0 = (const float*)d_in[1];
    const float* whh0 = (const float*)d_in[2];
    const float* bi0  = (const float*)d_in[3];
    const float* bh0  = (const float*)d_in[4];
    const float* wih1 = (const float*)d_in[5];
    const float* whh1 = (const float*)d_in[6];
    const float* bi1  = (const float*)d_in[7];
    const float* bh1  = (const float*)d_in[8];
    const float* wih2 = (const float*)d_in[9];
    const float* whh2 = (const float*)d_in[10];
    const float* bi2  = (const float*)d_in[11];
    const float* bh2  = (const float*)d_in[12];
    const float* W1   = (const float*)d_in[13];
    const float* b1   = (const float*)d_in[14];
    const float* W2   = (const float*)d_in[15];
    const float* b2   = (const float*)d_in[16];
    float* out = (float*)d_out;

    char* ws = (char*)d_ws;
    half_t* P    = (half_t*)ws;                               // 134,217,728 B
    half_t* W16  = (half_t*)(ws + 134217728);                 //   2,621,440 B
    float*  bias = (float*)(ws + 134217728 + 2621440);        //       6,144 B
    unsigned long long* X =
        (unsigned long long*)(ws + 134217728 + 2621440 + 8192);  // 1,048,576 B

    // dynamic-LDS opt-in (>64 KB); idempotent, not a stream op
    hipFuncSetAttribute((const void*)k_proj,
                        hipFuncAttributeMaxDynamicSharedMemorySize, 66560);

    k_cvt<<<5126, 256, 0, stream>>>(whh0, whh1, whh2, wih1, wih2,
                                    bi0, bh0, bi1, bh1, bi2, bh2, W16, bias, X);
    k_xp0<<<4096, 256, 0, stream>>>(x, wih0, bias, P);
    launch_scan(P, W16 + 0 * WN, X, 0,    stream);
    k_proj<<<2048, 256, 66560, stream>>>(P, W16 + 3 * WN, bias + 512);
    launch_scan(P, W16 + 1 * WN, X, 1024, stream);
    k_proj<<<2048, 256, 66560, stream>>>(P, W16 + 4 * WN, bias + 1024);
    launch_scan(P, W16 + 2 * WN, X, 2048, stream);
    k_head<<<128, 256, 0, stream>>>(P, W1, b1, W2, b2, out);
}